// Round 6
// baseline (576.811 us; speedup 1.0000x reference)
//
#include <hip/hip_runtime.h>
#include <stdint.h>

// MixHopNet, MI355X (gfx950). r4 (376us) PASSED; r5's slice-major rewrite
// failed with 1e37 garbage. r6 = r4 verbatim EXCEPT the propagate: 4 passes
// of 32 features, ROW-MAJOR in/out (pass offset ps*32), simple r3-style
// loop (thread = node x feature-pair, no slots/shuffles). Per-pass gather
// working set = 50000 x 64B lines = 3.2MB -> fits 4MB/XCD L2; edges/output
// use nontemporal hints so streaming traffic doesn't evict the slab.
// GEMM/softmax/preprocessing byte-identical to r4. ws layout unchanged.

#define NODES 50000
#define NEDGE 800000
#define NSB   ((NODES + 255) / 256)   // 196

typedef __bf16 bf16x8 __attribute__((ext_vector_type(8)));
typedef float  floatx4 __attribute__((ext_vector_type(4)));

__device__ __forceinline__ float bf2f(unsigned short u) {
  unsigned int x = ((unsigned int)u) << 16;
  return __builtin_bit_cast(float, x);
}
__device__ __forceinline__ unsigned short f2bf(float f) {
  unsigned int x = __builtin_bit_cast(unsigned int, f);
  x += 0x7FFFu + ((x >> 16) & 1u);   // RNE
  return (unsigned short)(x >> 16);
}
__device__ __forceinline__ float ldf(const void* p, size_t i, int f32) {
  return f32 ? ((const float*)p)[i] : bf2f(((const unsigned short*)p)[i]);
}
__device__ __forceinline__ float fin(float x) { return __builtin_isfinite(x) ? x : 0.f; }
__device__ __forceinline__ uint4 pack8(const float* f) {
  float4 a = ((const float4*)f)[0], b = ((const float4*)f)[1];
  uint4 r;
  r.x = (unsigned)f2bf(a.x) | ((unsigned)f2bf(a.y) << 16);
  r.y = (unsigned)f2bf(a.z) | ((unsigned)f2bf(a.w) << 16);
  r.z = (unsigned)f2bf(b.x) | ((unsigned)f2bf(b.y) << 16);
  r.w = (unsigned)f2bf(b.z) | ((unsigned)f2bf(b.w) << 16);
  return r;
}

// ---------------- graph preprocessing (identical to r4) ----------------

__global__ void k_count(const int* __restrict__ dst, int* __restrict__ cnt) {
  int e = blockIdx.x * blockDim.x + threadIdx.x;
  if (e < NEDGE) atomicAdd(&cnt[dst[e]], 1);
}

__global__ void k_scan_sum(const int* __restrict__ cnt, int* __restrict__ sums,
                           float* __restrict__ dinv,
                           const unsigned short* __restrict__ xs,
                           const unsigned short* __restrict__ ws_,
                           int* __restrict__ flags) {
  __shared__ int sdata[256];
  int t = threadIdx.x, idx = blockIdx.x * 256 + t;
  int c = (idx < NODES) ? cnt[idx] : 0;
  if (idx < NODES) dinv[idx] = rsqrtf((float)c + 1.0f);   // +1 self loop
  sdata[t] = c;
  __syncthreads();
  for (int off = 128; off; off >>= 1) {
    if (t < off) sdata[t] += sdata[t + off];
    __syncthreads();
  }
  if (t == 0) sums[blockIdx.x] = sdata[0];
  if (blockIdx.x == 0 && t < 64) {
    const unsigned short* ptrs[2] = {xs, ws_};
    for (int k = 0; k < 2; ++k) {
      int bad = 0;
      for (int i = 0; i < 4; ++i) {
        float v = bf2f(ptrs[k][t * 4 + i]);
        float a = fabsf(v);
        if (!(a <= 1e4f) || (v != 0.f && a < 1e-10f)) bad++;   // NaN fails a<=1e4
      }
      for (int off = 32; off; off >>= 1) bad += __shfl_xor(bad, off);
      if (t == 0) flags[k] = (bad > 16) ? 1 : 0;   // 1 = fp32
    }
  }
}

__global__ void k_scan_top(const int* __restrict__ sums, int* __restrict__ boff,
                           int* __restrict__ row_off) {
  __shared__ int sdata[256];
  int t = threadIdx.x;
  int v = (t < NSB) ? sums[t] : 0;
  int cur = v;
  sdata[t] = cur; __syncthreads();
  for (int off = 1; off < 256; off <<= 1) {
    int add = (t >= off) ? sdata[t - off] : 0;
    __syncthreads();
    cur += add; sdata[t] = cur;
    __syncthreads();
  }
  if (t < NSB) boff[t] = cur - v;           // exclusive
  if (t == NSB - 1) row_off[NODES] = cur;   // total == NEDGE
}

__global__ void k_scan_final(const int* __restrict__ cnt, const int* __restrict__ boff,
                             int* __restrict__ row_off) {
  __shared__ int sdata[256];
  int t = threadIdx.x, idx = blockIdx.x * 256 + t;
  int v = (idx < NODES) ? cnt[idx] : 0;
  int cur = v;
  sdata[t] = cur; __syncthreads();
  for (int off = 1; off < 256; off <<= 1) {
    int add = (t >= off) ? sdata[t - off] : 0;
    __syncthreads();
    cur += add; sdata[t] = cur;
    __syncthreads();
  }
  if (idx < NODES) row_off[idx] = boff[blockIdx.x] + cur - v;
}

#define FILL_BLOCKS (NEDGE / 256)   // 3125

__global__ void k_fill_prep(const int* __restrict__ src, const int* __restrict__ dst,
                            const int* __restrict__ row_off, int* __restrict__ cursor,
                            const float* __restrict__ dinv, unsigned int* __restrict__ edges,
                            const void* __restrict__ w1_0, const void* __restrict__ w1_1,
                            const void* __restrict__ w1_2, const void* __restrict__ w2_0,
                            const void* __restrict__ w2_1, const int* __restrict__ flags,
                            unsigned short* __restrict__ wt1, unsigned short* __restrict__ wt2) {
  if (blockIdx.x < FILL_BLOCKS) {
    int e = blockIdx.x * 256 + threadIdx.x;
    int s = src[e], d = dst[e];
    int pos = row_off[d] + atomicAdd(&cursor[d], 1);
    float w = dinv[s] * dinv[d];
    _Float16 hw = (_Float16)w;
    edges[pos] = ((unsigned int)__builtin_bit_cast(unsigned short, hw) << 16)
               | (unsigned int)(s & 0xFFFF);
  } else {
    int fw = flags[1];
    int idx = (blockIdx.x - FILL_BLOCKS) * 256 + threadIdx.x;
    if (idx < 3 * 128 * 128) {
      int g = idx / 16384, r = idx % 16384;
      int n = r / 128, k = r % 128;
      const void* w = (g == 0) ? w1_0 : (g == 1) ? w1_1 : w1_2;
      wt1[idx] = f2bf(ldf(w, (size_t)k * 128 + n, fw));
    } else {
      int r = idx - 49152;   // 312*256 - 49152 = 30720 = 80*384 exactly
      int n = r / 384, k = r % 384;
      float v = (n < 40) ? ldf(w2_0, (size_t)k * 40 + n, fw)
                         : ldf(w2_1, (size_t)k * 40 + (n - 40), fw);
      wt2[r] = f2bf(v);
    }
  }
}

__device__ __forceinline__ void unpack_edge(unsigned int e, int& s, float& w) {
  s = (int)(e & 0xFFFFu);
  w = (float)__builtin_bit_cast(_Float16, (unsigned short)(e >> 16));
}

// ---------------- 32-wide sliced propagate (row-major in/out) ----------------
// thread = (node, feature-pair): 16 threads per node, no slots/shuffles.
// Pass ps covers features [ps*32, ps*32+32): one 64B line per node per pass
// -> 3.2MB slab, L2-resident. Edges nt-loaded, output nt-stored so streaming
// traffic doesn't evict the slab. in/out both stride-128 row-major.
__global__ __launch_bounds__(256) void k_prop32s(
    const void* __restrict__ in, unsigned short* __restrict__ out, int off32,
    const int* __restrict__ row_off, const unsigned int* __restrict__ edges,
    const float* __restrict__ dinv, const int* __restrict__ flags, int ext) {
  int tid = blockIdx.x * 256 + threadIdx.x;
  int v = tid >> 4, fl = tid & 15;
  if (v >= NODES) return;
  int rb = row_off[v], re = row_off[v + 1];
  float dv = dinv[v];
  float wsw = dv * dv;
  float a0, a1;
  if (ext && (flags[0] != 0)) {   // fp32-input insurance path
    const float* inf = (const float*)in;
    float2 q = *(const float2*)(inf + (size_t)v * 128 + off32 + fl * 2);
    a0 = wsw * q.x; a1 = wsw * q.y;
    for (int j = rb; j < re; ++j) {
      unsigned int e = __builtin_nontemporal_load(&edges[j]);
      int s; float w; unpack_edge(e, s, w);
      float2 q2 = *(const float2*)(inf + (size_t)s * 128 + off32 + fl * 2);
      a0 += w * q2.x; a1 += w * q2.y;
    }
  } else {
    const unsigned short* inb = (const unsigned short*)in;
    unsigned int q = *(const unsigned int*)(inb + (size_t)v * 128 + off32 + fl * 2);
    a0 = wsw * bf2f((unsigned short)(q & 0xFFFF));
    a1 = wsw * bf2f((unsigned short)(q >> 16));
    for (int j = rb; j < re; ++j) {
      unsigned int e = __builtin_nontemporal_load(&edges[j]);
      int s; float w; unpack_edge(e, s, w);
      unsigned int q2 = *(const unsigned int*)(inb + (size_t)s * 128 + off32 + fl * 2);
      a0 += w * bf2f((unsigned short)(q2 & 0xFFFF));
      a1 += w * bf2f((unsigned short)(q2 >> 16));
    }
  }
  unsigned int o = ((unsigned int)f2bf(fin(a1)) << 16) | f2bf(fin(a0));
  __builtin_nontemporal_store(o, (unsigned int*)(out + (size_t)v * 128 + off32 + fl * 2));
}

// ---------------- fused conv1+conv2 (byte-identical to r4 — verified pass) --------
__global__ __launch_bounds__(256) void k_gemm_fused(
    const void* __restrict__ x, const unsigned short* __restrict__ x1,
    const unsigned short* __restrict__ x2, const unsigned short* __restrict__ wt1,
    const unsigned short* __restrict__ wt2,
    const unsigned short* __restrict__ b0, const unsigned short* __restrict__ b1,
    const unsigned short* __restrict__ b2, void* __restrict__ outp,
    unsigned short* __restrict__ z1, const int* __restrict__ flags) {
  __shared__ unsigned short lA[64 * 136];
  __shared__ unsigned short lW[128 * 136];
  __shared__ unsigned short lW2[80 * 136];
  int f32x = flags[0];
  int m0 = blockIdx.x * 64;
  int t = threadIdx.x;
  int wave = t >> 6, lane = t & 63;
  int lr = lane & 15, lq = lane >> 4;
  int wr = (wave >> 1) * 32, wc = (wave & 1) * 64;
  floatx4 zacc[5] = {};

  for (int g = 0; g < 3; ++g) {
    const unsigned short* Ab = (g == 0) ? (const unsigned short*)x : (g == 1) ? x1 : x2;
    const unsigned short* W = wt1 + g * 16384;
    const unsigned short* bias = (g == 0) ? b0 : (g == 1) ? b1 : b2;
    __syncthreads();
    for (int i = 0; i < 4; ++i) {            // A: 64 rows x 16 chunks
      int idx = t + i * 256;
      int row = idx >> 4, c16 = idx & 15;
      int gr = m0 + row;
      uint4 va = {0, 0, 0, 0};
      if (gr < NODES) {
        if (g == 0 && f32x) va = pack8((const float*)x + (size_t)gr * 128 + c16 * 8);
        else va = *(const uint4*)(Ab + (size_t)gr * 128 + c16 * 8);
      }
      *(uint4*)(&lA[row * 136 + c16 * 8]) = va;
    }
    for (int i = 0; i < 8; ++i) {            // W1: 128 x 16
      int idx = t + i * 256;
      int row = idx >> 4, c16 = idx & 15;
      *(uint4*)(&lW[row * 136 + c16 * 8]) =
          *(const uint4*)(W + row * 128 + c16 * 8);
    }
    for (int i = 0; i < 5; ++i) {            // W2 slice: 80 x 16
      int idx = t + i * 256;
      int n = idx >> 4, c16 = idx & 15;
      *(uint4*)(&lW2[n * 136 + c16 * 8]) =
          *(const uint4*)(wt2 + n * 384 + g * 128 + c16 * 8);
    }
    __syncthreads();

    floatx4 acc[2][4] = {};
    for (int ks = 0; ks < 4; ++ks) {
      int k0 = ks * 32 + lq * 8;
      bf16x8 af[2], bfr[4];
      for (int i = 0; i < 2; ++i)
        af[i] = *(const bf16x8*)(&lA[(wr + i * 16 + lr) * 136 + k0]);
      for (int j = 0; j < 4; ++j)
        bfr[j] = *(const bf16x8*)(&lW[(wc + j * 16 + lr) * 136 + k0]);
      for (int i = 0; i < 2; ++i)
        for (int j = 0; j < 4; ++j)
          acc[i][j] = __builtin_amdgcn_mfma_f32_16x16x32_bf16(af[i], bfr[j], acc[i][j], 0, 0, 0);
    }
    __syncthreads();
    for (int i = 0; i < 2; ++i) {
      int rloc = wr + i * 16 + lq * 4;
      for (int j = 0; j < 4; ++j) {
        int col = wc + j * 16 + lr;
        float bv = bf2f(bias[col]);
        for (int r = 0; r < 4; ++r) {
          float val = acc[i][j][r] + bv;
          val = val > 0.f ? val : 0.f;       // relu (squashes NaN too)
          lA[(rloc + r) * 136 + col] = f2bf(val);
        }
      }
    }
    __syncthreads();
    for (int ks = 0; ks < 4; ++ks) {
      int k0 = ks * 32 + lq * 8;
      bf16x8 ah = *(const bf16x8*)(&lA[(wave * 16 + lr) * 136 + k0]);
      bf16x8 bw[5];
      for (int j = 0; j < 5; ++j)
        bw[j] = *(const bf16x8*)(&lW2[(j * 16 + lr) * 136 + k0]);
      for (int j = 0; j < 5; ++j)
        zacc[j] = __builtin_amdgcn_mfma_f32_16x16x32_bf16(ah, bw[j], zacc[j], 0, 0, 0);
    }
  }
  int rbase = m0 + wave * 16 + lq * 4;
  for (int j = 0; j < 5; ++j) {
    int col = j * 16 + lr;
    for (int r = 0; r < 4; ++r) {
      int gr = rbase + r;
      if (gr < NODES) {
        float vv = zacc[j][r];
        if (col < 40) {
          if (f32x) ((float*)outp)[(size_t)gr * 80 + col] = vv;
          else ((unsigned short*)outp)[(size_t)gr * 80 + col] = f2bf(vv);
        } else {
          z1[(size_t)gr * 40 + (col - 40)] = f2bf(vv);
        }
      }
    }
  }
}

// ---------------- fused 40-d propagate + bias + log_softmax (identical to r4) ------
__global__ __launch_bounds__(256) void k_prop40_softmax(
    const unsigned short* __restrict__ z1, const unsigned short* __restrict__ b2_0,
    const unsigned short* __restrict__ b2_1, const int* __restrict__ row_off,
    const unsigned int* __restrict__ edges, const float* __restrict__ dinv,
    void* __restrict__ outp, const int* __restrict__ flags) {
  int f32o = flags[0];
  int v = blockIdx.x * 4 + (threadIdx.x >> 6);
  if (v >= NODES) return;
  int lane = threadIdx.x & 63;
  int slot = lane >> 5, fl = lane & 31;
  bool gact = fl < 20;
  int fo = gact ? fl * 2 : 0;
  int rb = row_off[v], re = row_off[v + 1];
  float dv = dinv[v];
  float wsw = dv * dv;
  float ax = 0.f, ay = 0.f;
  if (slot == 0) {
    unsigned int p = *(const unsigned int*)(z1 + (size_t)v * 40 + fo);
    ax = wsw * bf2f((unsigned short)(p & 0xFFFF));
    ay = wsw * bf2f((unsigned short)(p >> 16));
  }
  for (int j = rb + slot; j < re; j += 2) {
    int s; float w; unpack_edge(edges[j], s, w);
    unsigned int q = *(const unsigned int*)(z1 + (size_t)s * 40 + fo);
    ax += w * bf2f((unsigned short)(q & 0xFFFF));
    ay += w * bf2f((unsigned short)(q >> 16));
  }
  ax += __shfl_xor(ax, 32);
  ay += __shfl_xor(ay, 32);
  bool act = lane < 20;
  float l0x = 0.f, l0y = 0.f, l1x = 0.f, l1y = 0.f;
  if (act) {
    l0x = fin(ldf(outp, (size_t)v * 80 + fo, f32o)     + bf2f(b2_0[fo]));
    l0y = fin(ldf(outp, (size_t)v * 80 + fo + 1, f32o) + bf2f(b2_0[fo + 1]));
    l1x = fin(ax + bf2f(b2_1[fo]));
    l1y = fin(ay + bf2f(b2_1[fo + 1]));
  }
  float m = act ? fmaxf(fmaxf(l0x, l0y), fmaxf(l1x, l1y)) : -INFINITY;
  for (int off = 32; off; off >>= 1) m = fmaxf(m, __shfl_xor(m, off));
  float s = act ? (expf(l0x - m) + expf(l0y - m) + expf(l1x - m) + expf(l1y - m)) : 0.f;
  for (int off = 32; off; off >>= 1) s += __shfl_xor(s, off);
  float lse = m + logf(s);
  if (act) {
    if (f32o) {
      float* of = (float*)outp;
      of[(size_t)v * 80 + fo]          = l0x - lse;
      of[(size_t)v * 80 + fo + 1]      = l0y - lse;
      of[(size_t)v * 80 + 40 + fo]     = l1x - lse;
      of[(size_t)v * 80 + 40 + fo + 1] = l1y - lse;
    } else {
      unsigned short* ob = (unsigned short*)outp;
      unsigned int o0 = ((unsigned int)f2bf(l0y - lse) << 16) | f2bf(l0x - lse);
      unsigned int o1 = ((unsigned int)f2bf(l1y - lse) << 16) | f2bf(l1x - lse);
      *(unsigned int*)(ob + (size_t)v * 80 + fo) = o0;
      *(unsigned int*)(ob + (size_t)v * 80 + 40 + fo) = o1;
    }
  }
}

// sentinel: ws too small — encode its MB count into the output
__global__ void k_sentinel(unsigned short* o, int n, float val) {
  int i = blockIdx.x * blockDim.x + threadIdx.x;
  if (i < n) o[i] = f2bf(val);
}

// ---------------- host ----------------

static inline size_t al256(size_t x) { return (x + 255) & ~(size_t)255; }

extern "C" void kernel_launch(void* const* d_in, const int* in_sizes, int n_in,
                              void* d_out, int out_size, void* d_ws, size_t ws_size,
                              hipStream_t stream) {
  const void* x    = d_in[0];
  const int*  ei   = (const int*)d_in[1];
  const void* w1_0 = d_in[2];
  const unsigned short* b1_0 = (const unsigned short*)d_in[3];
  const void* w1_1 = d_in[4];
  const unsigned short* b1_1 = (const unsigned short*)d_in[5];
  const void* w1_2 = d_in[6];
  const unsigned short* b1_2 = (const unsigned short*)d_in[7];
  const void* w2_0 = d_in[8];
  const unsigned short* b2_0 = (const unsigned short*)d_in[9];
  const void* w2_1 = d_in[10];
  const unsigned short* b2_1 = (const unsigned short*)d_in[11];
  const int* srcv = ei;
  const int* dstv = ei + NEDGE;

  // ws layout IDENTICAL to r3/r4 (33.8 MB); x1v/x2v row-major [N][128]
  char* p = (char*)d_ws;
  int*   flags   = (int*)p;               p += al256(2 * 4);
  int*   row_off = (int*)p;               p += al256((NODES + 1) * 4);
  float* dinv    = (float*)p;             p += al256(NODES * 4);
  unsigned int* edges = (unsigned int*)p; p += al256((size_t)NEDGE * 4);
  unsigned short* wt1 = (unsigned short*)p; p += al256(3 * 128 * 128 * 2);
  unsigned short* wt2 = (unsigned short*)p; p += al256(80 * 384 * 2);
  unsigned short* x1v = (unsigned short*)p; p += al256((size_t)NODES * 128 * 2);
  unsigned short* x2v = (unsigned short*)p; p += al256((size_t)NODES * 128 * 2);
  unsigned short* z1  = (unsigned short*)p; p += al256((size_t)NODES * 40 * 2);
  int*   cnt     = (int*)p;               p += al256(NODES * 4);
  int*   cursor  = (int*)p;               p += al256(NODES * 4);
  int*   sums    = (int*)p;               p += al256(NSB * 4);
  int*   boff    = (int*)p;               p += al256(NSB * 4);
  size_t need = (size_t)(p - (char*)d_ws);

  if (ws_size < need) {
    float val = -1000.f - (float)(ws_size >> 20);
    k_sentinel<<<(out_size + 255) / 256, 256, 0, stream>>>(
        (unsigned short*)d_out, out_size, val);
    return;
  }

  hipMemsetAsync(cnt, 0, al256(NODES * 4) + NODES * 4, stream);
  k_count<<<NEDGE / 256, 256, 0, stream>>>(dstv, cnt);
  k_scan_sum<<<NSB, 256, 0, stream>>>(cnt, sums, dinv,
                                      (const unsigned short*)x,
                                      (const unsigned short*)w1_0, flags);
  k_scan_top<<<1, 256, 0, stream>>>(sums, boff, row_off);
  k_scan_final<<<NSB, 256, 0, stream>>>(cnt, boff, row_off);
  k_fill_prep<<<FILL_BLOCKS + 312, 256, 0, stream>>>(
      srcv, dstv, row_off, cursor, dinv, edges,
      w1_0, w1_1, w1_2, w2_0, w2_1, flags, wt1, wt2);
  // prop1: x[:, ps*32 : ps*32+32] -> x1v same columns (row-major both sides)
  for (int ps = 0; ps < 4; ++ps)
    k_prop32s<<<NODES * 16 / 256, 256, 0, stream>>>(
        x, x1v, ps * 32, row_off, edges, dinv, flags, 1);
  // prop2: x1v -> x2v, same slicing
  for (int ps = 0; ps < 4; ++ps)
    k_prop32s<<<NODES * 16 / 256, 256, 0, stream>>>(
        x1v, x2v, ps * 32, row_off, edges, dinv, flags, 0);
  k_gemm_fused<<<(NODES + 63) / 64, 256, 0, stream>>>(x, x1v, x2v, wt1, wt2,
                                                      b1_0, b1_1, b1_2, d_out, z1, flags);
  k_prop40_softmax<<<NODES / 4, 256, 0, stream>>>(z1, b2_0, b2_1, row_off, edges,
                                                  dinv, d_out, flags);
}

// Round 7
// 370.092 us; speedup vs baseline: 1.5586x; 1.5586x over previous
//
#include <hip/hip_runtime.h>
#include <stdint.h>

// MixHopNet, MI355X (gfx950). Best = r4 (376us). r5 (slice-major) failed,
// r6 (row-major slices) regressed to 577us: 64B@256B-stride slices still
// thrash L2 (line granularity) -> 8 passes re-pay full fabric traffic.
// Slicing abandoned. r7 = r4 verbatim EXCEPT:
//  (1) gemm A-fragments loaded DIRECT from global (L2/L3-resident; removes
//      A-stage + 3 barriers/hop; gemm was ~90us, barrier/staging-bound).
//  (2) softmax edge loop unrolled x2 (independent acc pairs; was 56us,
//      VALU 35%, latency-bound serial FMA chain).
// prop128 / preprocessing / ws layout byte-identical to r4 (33.8 MB).

#define NODES 50000
#define NEDGE 800000
#define NSB   ((NODES + 255) / 256)   // 196

typedef __bf16 bf16x8 __attribute__((ext_vector_type(8)));
typedef float  floatx4 __attribute__((ext_vector_type(4)));

__device__ __forceinline__ float bf2f(unsigned short u) {
  unsigned int x = ((unsigned int)u) << 16;
  return __builtin_bit_cast(float, x);
}
__device__ __forceinline__ unsigned short f2bf(float f) {
  unsigned int x = __builtin_bit_cast(unsigned int, f);
  x += 0x7FFFu + ((x >> 16) & 1u);   // RNE
  return (unsigned short)(x >> 16);
}
__device__ __forceinline__ float ldf(const void* p, size_t i, int f32) {
  return f32 ? ((const float*)p)[i] : bf2f(((const unsigned short*)p)[i]);
}
__device__ __forceinline__ float fin(float x) { return __builtin_isfinite(x) ? x : 0.f; }
__device__ __forceinline__ uint4 pack8(const float* f) {
  float4 a = ((const float4*)f)[0], b = ((const float4*)f)[1];
  uint4 r;
  r.x = (unsigned)f2bf(a.x) | ((unsigned)f2bf(a.y) << 16);
  r.y = (unsigned)f2bf(a.z) | ((unsigned)f2bf(a.w) << 16);
  r.z = (unsigned)f2bf(b.x) | ((unsigned)f2bf(b.y) << 16);
  r.w = (unsigned)f2bf(b.z) | ((unsigned)f2bf(b.w) << 16);
  return r;
}
__device__ __forceinline__ void macc8(uint4 q, float* a, float w) {
  a[0] += w * bf2f((unsigned short)(q.x & 0xFFFF));
  a[1] += w * bf2f((unsigned short)(q.x >> 16));
  a[2] += w * bf2f((unsigned short)(q.y & 0xFFFF));
  a[3] += w * bf2f((unsigned short)(q.y >> 16));
  a[4] += w * bf2f((unsigned short)(q.z & 0xFFFF));
  a[5] += w * bf2f((unsigned short)(q.z >> 16));
  a[6] += w * bf2f((unsigned short)(q.w & 0xFFFF));
  a[7] += w * bf2f((unsigned short)(q.w >> 16));
}

// ---------------- graph preprocessing (identical to r4) ----------------

__global__ void k_count(const int* __restrict__ dst, int* __restrict__ cnt) {
  int e = blockIdx.x * blockDim.x + threadIdx.x;
  if (e < NEDGE) atomicAdd(&cnt[dst[e]], 1);
}

__global__ void k_scan_sum(const int* __restrict__ cnt, int* __restrict__ sums,
                           float* __restrict__ dinv,
                           const unsigned short* __restrict__ xs,
                           const unsigned short* __restrict__ ws_,
                           int* __restrict__ flags) {
  __shared__ int sdata[256];
  int t = threadIdx.x, idx = blockIdx.x * 256 + t;
  int c = (idx < NODES) ? cnt[idx] : 0;
  if (idx < NODES) dinv[idx] = rsqrtf((float)c + 1.0f);   // +1 self loop
  sdata[t] = c;
  __syncthreads();
  for (int off = 128; off; off >>= 1) {
    if (t < off) sdata[t] += sdata[t + off];
    __syncthreads();
  }
  if (t == 0) sums[blockIdx.x] = sdata[0];
  if (blockIdx.x == 0 && t < 64) {
    const unsigned short* ptrs[2] = {xs, ws_};
    for (int k = 0; k < 2; ++k) {
      int bad = 0;
      for (int i = 0; i < 4; ++i) {
        float v = bf2f(ptrs[k][t * 4 + i]);
        float a = fabsf(v);
        if (!(a <= 1e4f) || (v != 0.f && a < 1e-10f)) bad++;   // NaN fails a<=1e4
      }
      for (int off = 32; off; off >>= 1) bad += __shfl_xor(bad, off);
      if (t == 0) flags[k] = (bad > 16) ? 1 : 0;   // 1 = fp32
    }
  }
}

__global__ void k_scan_top(const int* __restrict__ sums, int* __restrict__ boff,
                           int* __restrict__ row_off) {
  __shared__ int sdata[256];
  int t = threadIdx.x;
  int v = (t < NSB) ? sums[t] : 0;
  int cur = v;
  sdata[t] = cur; __syncthreads();
  for (int off = 1; off < 256; off <<= 1) {
    int add = (t >= off) ? sdata[t - off] : 0;
    __syncthreads();
    cur += add; sdata[t] = cur;
    __syncthreads();
  }
  if (t < NSB) boff[t] = cur - v;           // exclusive
  if (t == NSB - 1) row_off[NODES] = cur;   // total == NEDGE
}

__global__ void k_scan_final(const int* __restrict__ cnt, const int* __restrict__ boff,
                             int* __restrict__ row_off) {
  __shared__ int sdata[256];
  int t = threadIdx.x, idx = blockIdx.x * 256 + t;
  int v = (idx < NODES) ? cnt[idx] : 0;
  int cur = v;
  sdata[t] = cur; __syncthreads();
  for (int off = 1; off < 256; off <<= 1) {
    int add = (t >= off) ? sdata[t - off] : 0;
    __syncthreads();
    cur += add; sdata[t] = cur;
    __syncthreads();
  }
  if (idx < NODES) row_off[idx] = boff[blockIdx.x] + cur - v;
}

#define FILL_BLOCKS (NEDGE / 256)   // 3125

__global__ void k_fill_prep(const int* __restrict__ src, const int* __restrict__ dst,
                            const int* __restrict__ row_off, int* __restrict__ cursor,
                            const float* __restrict__ dinv, unsigned int* __restrict__ edges,
                            const void* __restrict__ w1_0, const void* __restrict__ w1_1,
                            const void* __restrict__ w1_2, const void* __restrict__ w2_0,
                            const void* __restrict__ w2_1, const int* __restrict__ flags,
                            unsigned short* __restrict__ wt1, unsigned short* __restrict__ wt2) {
  if (blockIdx.x < FILL_BLOCKS) {
    int e = blockIdx.x * 256 + threadIdx.x;
    int s = src[e], d = dst[e];
    int pos = row_off[d] + atomicAdd(&cursor[d], 1);
    float w = dinv[s] * dinv[d];
    _Float16 hw = (_Float16)w;
    edges[pos] = ((unsigned int)__builtin_bit_cast(unsigned short, hw) << 16)
               | (unsigned int)(s & 0xFFFF);
  } else {
    int fw = flags[1];
    int idx = (blockIdx.x - FILL_BLOCKS) * 256 + threadIdx.x;
    if (idx < 3 * 128 * 128) {
      int g = idx / 16384, r = idx % 16384;
      int n = r / 128, k = r % 128;
      const void* w = (g == 0) ? w1_0 : (g == 1) ? w1_1 : w1_2;
      wt1[idx] = f2bf(ldf(w, (size_t)k * 128 + n, fw));
    } else {
      int r = idx - 49152;   // 312*256 - 49152 = 30720 = 80*384 exactly
      int n = r / 384, k = r % 384;
      float v = (n < 40) ? ldf(w2_0, (size_t)k * 40 + n, fw)
                         : ldf(w2_1, (size_t)k * 40 + (n - 40), fw);
      wt2[r] = f2bf(v);
    }
  }
}

__device__ __forceinline__ void unpack_edge(unsigned int e, int& s, float& w) {
  s = (int)(e & 0xFFFFu);
  w = (float)__builtin_bit_cast(_Float16, (unsigned short)(e >> 16));
}

// ---------------- 128-wide propagate (identical to r4) ----------------
__global__ __launch_bounds__(256) void k_prop128(
    const void* __restrict__ in, unsigned short* __restrict__ out,
    const int* __restrict__ row_off, const unsigned int* __restrict__ edges,
    const float* __restrict__ dinv, const int* __restrict__ flags, int ext) {
  int v = blockIdx.x * 4 + (threadIdx.x >> 6);
  if (v >= NODES) return;
  int lane = threadIdx.x & 63;
  int rb = row_off[v], re = row_off[v + 1];
  float dv = dinv[v];
  float wsw = dv * dv;
  int f32 = ext && (flags[0] != 0);
  if (f32) {   // fp32-input insurance path (never taken for this dataset)
    const float* inf = (const float*)in;
    float2 tt = *(const float2*)(inf + (size_t)v * 128 + lane * 2);
    float ax = wsw * tt.x, ay = wsw * tt.y;
    for (int j = rb; j < re; ++j) {
      int s; float w; unpack_edge(edges[j], s, w);
      float2 q = *(const float2*)(inf + (size_t)s * 128 + lane * 2);
      ax += w * q.x; ay += w * q.y;
    }
    ax = fin(ax); ay = fin(ay);
    unsigned int o = ((unsigned int)f2bf(ay) << 16) | f2bf(ax);
    *(unsigned int*)(out + (size_t)v * 128 + lane * 2) = o;
    return;
  }
  const unsigned short* inb = (const unsigned short*)in;
  int slot = lane >> 4, fl = lane & 15;
  float acc[8];
  {
    uint4 q = *(const uint4*)(inb + (size_t)v * 128 + fl * 8);
    float sw = (slot == 0) ? wsw : 0.f;
    acc[0] = sw * bf2f((unsigned short)(q.x & 0xFFFF));
    acc[1] = sw * bf2f((unsigned short)(q.x >> 16));
    acc[2] = sw * bf2f((unsigned short)(q.y & 0xFFFF));
    acc[3] = sw * bf2f((unsigned short)(q.y >> 16));
    acc[4] = sw * bf2f((unsigned short)(q.z & 0xFFFF));
    acc[5] = sw * bf2f((unsigned short)(q.z >> 16));
    acc[6] = sw * bf2f((unsigned short)(q.w & 0xFFFF));
    acc[7] = sw * bf2f((unsigned short)(q.w >> 16));
  }
  for (int j = rb + slot; j < re; j += 4) {
    int s; float w; unpack_edge(edges[j], s, w);
    uint4 q = *(const uint4*)(inb + (size_t)s * 128 + fl * 8);
    macc8(q, acc, w);
  }
  #pragma unroll
  for (int k = 0; k < 8; ++k) {
    acc[k] += __shfl_xor(acc[k], 32);
    acc[k] += __shfl_xor(acc[k], 16);
  }
  if (slot == 0) {
    #pragma unroll
    for (int k = 0; k < 8; ++k) acc[k] = fin(acc[k]);
    uint4 o = pack8(acc);
    *(uint4*)(out + (size_t)v * 128 + fl * 8) = o;
  }
}

// ---------------- fused conv1+conv2 ----------------
// r7: A-fragments loaded direct from global (L2/L3-resident rows, 16B-aligned
// per-lane loads). lA holds only the h round-trip. 2 barriers per hop.
__global__ __launch_bounds__(256) void k_gemm_fused(
    const void* __restrict__ x, const unsigned short* __restrict__ x1,
    const unsigned short* __restrict__ x2, const unsigned short* __restrict__ wt1,
    const unsigned short* __restrict__ wt2,
    const unsigned short* __restrict__ b0, const unsigned short* __restrict__ b1,
    const unsigned short* __restrict__ b2, void* __restrict__ outp,
    unsigned short* __restrict__ z1, const int* __restrict__ flags) {
  __shared__ unsigned short lA[64 * 136];    // h tile only
  __shared__ unsigned short lW[128 * 136];   // W1_g [n][k]
  __shared__ unsigned short lW2[80 * 136];   // W2 slice [n][kk]
  int f32x = flags[0];
  int m0 = blockIdx.x * 64;
  int t = threadIdx.x;
  int wave = t >> 6, lane = t & 63;
  int lr = lane & 15, lq = lane >> 4;
  int wr = (wave >> 1) * 32, wc = (wave & 1) * 64;
  floatx4 zacc[5] = {};

  for (int g = 0; g < 3; ++g) {
    const unsigned short* Ab = (g == 0) ? (const unsigned short*)x : (g == 1) ? x1 : x2;
    const unsigned short* W = wt1 + g * 16384;
    const unsigned short* bias = (g == 0) ? b0 : (g == 1) ? b1 : b2;
    __syncthreads();   // prior z-phase lW2/lA reads complete
    for (int i = 0; i < 8; ++i) {            // W1: 128 x 16 chunks
      int idx = t + i * 256;
      int row = idx >> 4, c16 = idx & 15;
      *(uint4*)(&lW[row * 136 + c16 * 8]) =
          *(const uint4*)(W + row * 128 + c16 * 8);
    }
    for (int i = 0; i < 5; ++i) {            // W2 slice: 80 x 16
      int idx = t + i * 256;
      int n = idx >> 4, c16 = idx & 15;
      *(uint4*)(&lW2[n * 136 + c16 * 8]) =
          *(const uint4*)(wt2 + n * 384 + g * 128 + c16 * 8);
    }
    __syncthreads();

    // h-phase: A fragments straight from global
    floatx4 acc[2][4] = {};
    for (int ks = 0; ks < 4; ++ks) {
      int k0 = ks * 32 + lq * 8;
      bf16x8 af[2], bfr[4];
      for (int i = 0; i < 2; ++i) {
        int gr = m0 + wr + i * 16 + lr;
        if (gr < NODES) {
          if (g == 0 && f32x) {
            uint4 t4 = pack8((const float*)x + (size_t)gr * 128 + k0);
            af[i] = __builtin_bit_cast(bf16x8, t4);
          } else {
            af[i] = *(const bf16x8*)(Ab + (size_t)gr * 128 + k0);
          }
        } else {
          uint4 zz = {0, 0, 0, 0};
          af[i] = __builtin_bit_cast(bf16x8, zz);
        }
      }
      for (int j = 0; j < 4; ++j)
        bfr[j] = *(const bf16x8*)(&lW[(wc + j * 16 + lr) * 136 + k0]);
      for (int i = 0; i < 2; ++i)
        for (int j = 0; j < 4; ++j)
          acc[i][j] = __builtin_amdgcn_mfma_f32_16x16x32_bf16(af[i], bfr[j], acc[i][j], 0, 0, 0);
    }
    // h -> LDS (lA free: last reads were before top-of-loop barrier)
    for (int i = 0; i < 2; ++i) {
      int rloc = wr + i * 16 + lq * 4;
      for (int j = 0; j < 4; ++j) {
        int col = wc + j * 16 + lr;
        float bv = bf2f(bias[col]);
        for (int r = 0; r < 4; ++r) {
          float val = acc[i][j][r] + bv;
          val = val > 0.f ? val : 0.f;       // relu (squashes NaN too)
          lA[(rloc + r) * 136 + col] = f2bf(val);
        }
      }
    }
    __syncthreads();
    // z-phase
    for (int ks = 0; ks < 4; ++ks) {
      int k0 = ks * 32 + lq * 8;
      bf16x8 ah = *(const bf16x8*)(&lA[(wave * 16 + lr) * 136 + k0]);
      bf16x8 bw[5];
      for (int j = 0; j < 5; ++j)
        bw[j] = *(const bf16x8*)(&lW2[(j * 16 + lr) * 136 + k0]);
      for (int j = 0; j < 5; ++j)
        zacc[j] = __builtin_amdgcn_mfma_f32_16x16x32_bf16(ah, bw[j], zacc[j], 0, 0, 0);
    }
  }
  int rbase = m0 + wave * 16 + lq * 4;
  for (int j = 0; j < 5; ++j) {
    int col = j * 16 + lr;
    for (int r = 0; r < 4; ++r) {
      int gr = rbase + r;
      if (gr < NODES) {
        float vv = zacc[j][r];
        if (col < 40) {
          if (f32x) ((float*)outp)[(size_t)gr * 80 + col] = vv;
          else ((unsigned short*)outp)[(size_t)gr * 80 + col] = f2bf(vv);
        } else {
          z1[(size_t)gr * 40 + (col - 40)] = f2bf(vv);
        }
      }
    }
  }
}

// ---------------- fused 40-d propagate + bias + log_softmax ----------------
// r7: edge loop unrolled x2 per slot (independent accumulator pairs)
__global__ __launch_bounds__(256) void k_prop40_softmax(
    const unsigned short* __restrict__ z1, const unsigned short* __restrict__ b2_0,
    const unsigned short* __restrict__ b2_1, const int* __restrict__ row_off,
    const unsigned int* __restrict__ edges, const float* __restrict__ dinv,
    void* __restrict__ outp, const int* __restrict__ flags) {
  int f32o = flags[0];
  int v = blockIdx.x * 4 + (threadIdx.x >> 6);
  if (v >= NODES) return;
  int lane = threadIdx.x & 63;
  int slot = lane >> 5, fl = lane & 31;
  bool gact = fl < 20;
  int fo = gact ? fl * 2 : 0;
  int rb = row_off[v], re = row_off[v + 1];
  float dv = dinv[v];
  float wsw = dv * dv;
  float ax = 0.f, ay = 0.f, bx = 0.f, by = 0.f;
  if (slot == 0) {
    unsigned int p = *(const unsigned int*)(z1 + (size_t)v * 40 + fo);
    ax = wsw * bf2f((unsigned short)(p & 0xFFFF));
    ay = wsw * bf2f((unsigned short)(p >> 16));
  }
  int j = rb + slot;
  for (; j + 2 < re; j += 4) {   // two stride-2 steps per iteration
    int s1; float w1; unpack_edge(edges[j], s1, w1);
    int s2; float w2; unpack_edge(edges[j + 2], s2, w2);
    unsigned int q1 = *(const unsigned int*)(z1 + (size_t)s1 * 40 + fo);
    unsigned int q2 = *(const unsigned int*)(z1 + (size_t)s2 * 40 + fo);
    ax += w1 * bf2f((unsigned short)(q1 & 0xFFFF));
    ay += w1 * bf2f((unsigned short)(q1 >> 16));
    bx += w2 * bf2f((unsigned short)(q2 & 0xFFFF));
    by += w2 * bf2f((unsigned short)(q2 >> 16));
  }
  if (j < re) {
    int s; float w; unpack_edge(edges[j], s, w);
    unsigned int q = *(const unsigned int*)(z1 + (size_t)s * 40 + fo);
    ax += w * bf2f((unsigned short)(q & 0xFFFF));
    ay += w * bf2f((unsigned short)(q >> 16));
  }
  ax += bx; ay += by;
  ax += __shfl_xor(ax, 32);
  ay += __shfl_xor(ay, 32);
  bool act = lane < 20;
  float l0x = 0.f, l0y = 0.f, l1x = 0.f, l1y = 0.f;
  if (act) {
    l0x = fin(ldf(outp, (size_t)v * 80 + fo, f32o)     + bf2f(b2_0[fo]));
    l0y = fin(ldf(outp, (size_t)v * 80 + fo + 1, f32o) + bf2f(b2_0[fo + 1]));
    l1x = fin(ax + bf2f(b2_1[fo]));
    l1y = fin(ay + bf2f(b2_1[fo + 1]));
  }
  float m = act ? fmaxf(fmaxf(l0x, l0y), fmaxf(l1x, l1y)) : -INFINITY;
  for (int off = 32; off; off >>= 1) m = fmaxf(m, __shfl_xor(m, off));
  float s = act ? (expf(l0x - m) + expf(l0y - m) + expf(l1x - m) + expf(l1y - m)) : 0.f;
  for (int off = 32; off; off >>= 1) s += __shfl_xor(s, off);
  float lse = m + logf(s);
  if (act) {
    if (f32o) {
      float* of = (float*)outp;
      of[(size_t)v * 80 + fo]          = l0x - lse;
      of[(size_t)v * 80 + fo + 1]      = l0y - lse;
      of[(size_t)v * 80 + 40 + fo]     = l1x - lse;
      of[(size_t)v * 80 + 40 + fo + 1] = l1y - lse;
    } else {
      unsigned short* ob = (unsigned short*)outp;
      unsigned int o0 = ((unsigned int)f2bf(l0y - lse) << 16) | f2bf(l0x - lse);
      unsigned int o1 = ((unsigned int)f2bf(l1y - lse) << 16) | f2bf(l1x - lse);
      *(unsigned int*)(ob + (size_t)v * 80 + fo) = o0;
      *(unsigned int*)(ob + (size_t)v * 80 + 40 + fo) = o1;
    }
  }
}

// sentinel: ws too small — encode its MB count into the output
__global__ void k_sentinel(unsigned short* o, int n, float val) {
  int i = blockIdx.x * blockDim.x + threadIdx.x;
  if (i < n) o[i] = f2bf(val);
}

// ---------------- host ----------------

static inline size_t al256(size_t x) { return (x + 255) & ~(size_t)255; }

extern "C" void kernel_launch(void* const* d_in, const int* in_sizes, int n_in,
                              void* d_out, int out_size, void* d_ws, size_t ws_size,
                              hipStream_t stream) {
  const void* x    = d_in[0];
  const int*  ei   = (const int*)d_in[1];
  const void* w1_0 = d_in[2];
  const unsigned short* b1_0 = (const unsigned short*)d_in[3];
  const void* w1_1 = d_in[4];
  const unsigned short* b1_1 = (const unsigned short*)d_in[5];
  const void* w1_2 = d_in[6];
  const unsigned short* b1_2 = (const unsigned short*)d_in[7];
  const void* w2_0 = d_in[8];
  const unsigned short* b2_0 = (const unsigned short*)d_in[9];
  const void* w2_1 = d_in[10];
  const unsigned short* b2_1 = (const unsigned short*)d_in[11];
  const int* srcv = ei;
  const int* dstv = ei + NEDGE;

  // ws layout IDENTICAL to r3/r4 (33.8 MB)
  char* p = (char*)d_ws;
  int*   flags   = (int*)p;               p += al256(2 * 4);
  int*   row_off = (int*)p;               p += al256((NODES + 1) * 4);
  float* dinv    = (float*)p;             p += al256(NODES * 4);
  unsigned int* edges = (unsigned int*)p; p += al256((size_t)NEDGE * 4);
  unsigned short* wt1 = (unsigned short*)p; p += al256(3 * 128 * 128 * 2);
  unsigned short* wt2 = (unsigned short*)p; p += al256(80 * 384 * 2);
  unsigned short* x1v = (unsigned short*)p; p += al256((size_t)NODES * 128 * 2);
  unsigned short* x2v = (unsigned short*)p; p += al256((size_t)NODES * 128 * 2);
  unsigned short* z1  = (unsigned short*)p; p += al256((size_t)NODES * 40 * 2);
  int*   cnt     = (int*)p;               p += al256(NODES * 4);
  int*   cursor  = (int*)p;               p += al256(NODES * 4);
  int*   sums    = (int*)p;               p += al256(NSB * 4);
  int*   boff    = (int*)p;               p += al256(NSB * 4);
  size_t need = (size_t)(p - (char*)d_ws);

  if (ws_size < need) {
    float val = -1000.f - (float)(ws_size >> 20);
    k_sentinel<<<(out_size + 255) / 256, 256, 0, stream>>>(
        (unsigned short*)d_out, out_size, val);
    return;
  }

  hipMemsetAsync(cnt, 0, al256(NODES * 4) + NODES * 4, stream);
  k_count<<<NEDGE / 256, 256, 0, stream>>>(dstv, cnt);
  k_scan_sum<<<NSB, 256, 0, stream>>>(cnt, sums, dinv,
                                      (const unsigned short*)x,
                                      (const unsigned short*)w1_0, flags);
  k_scan_top<<<1, 256, 0, stream>>>(sums, boff, row_off);
  k_scan_final<<<NSB, 256, 0, stream>>>(cnt, boff, row_off);
  k_fill_prep<<<FILL_BLOCKS + 312, 256, 0, stream>>>(
      srcv, dstv, row_off, cursor, dinv, edges,
      w1_0, w1_1, w1_2, w2_0, w2_1, flags, wt1, wt2);
  k_prop128<<<NODES / 4, 256, 0, stream>>>(x, x1v, row_off, edges, dinv, flags, 1);
  k_prop128<<<NODES / 4, 256, 0, stream>>>(x1v, x2v, row_off, edges, dinv, flags, 0);
  k_gemm_fused<<<(NODES + 63) / 64, 256, 0, stream>>>(x, x1v, x2v, wt1, wt2,
                                                      b1_0, b1_1, b1_2, d_out, z1, flags);
  k_prop40_softmax<<<NODES / 4, 256, 0, stream>>>(z1, b2_0, b2_1, row_off, edges,
                                                  dinv, d_out, flags);
}